// Round 5
// baseline (888.855 us; speedup 1.0000x reference)
//
#include <hip/hip_runtime.h>
#include <cstdint>

// SNN autoencoder, MI355X. 4 kernels:
//  K0 splitW : dec_w2 (fp32) -> hi/lo bf16 pair (exact to 2^-18 rel)
//  K1 phaseA : x_in = x @ enc_w1^T + enc_b1, exact fp32 tiled GEMM
//  K2 phaseB : per-sample LIF recurrence (wave/sample, state in regs),
//              emits d1 spike masks (16 t x 128 bits per sample)
//  K3 phaseC : out = mean_t sigmoid(spikes_t @ dec_w2^T + dec_b2) via bf16 MFMA
//              (A is 0/1 -> exact in bf16; W split hi+lo -> 2^-18 rel error)
// ws layout (needs 25,567,232 bytes; guarded in kernel_launch):
//  [0, 16MB)        x_in  fp32 [32768][128]
//  [16MB, 24MB)     masks ulonglong2 [32768][16]
//  [24MB..]         w2hi, w2lo ushort [784][128] each

using short8 = __attribute__((ext_vector_type(8))) short;
using f32x4  = __attribute__((ext_vector_type(4))) float;

#define XIN_OFF   0u
#define MASK_OFF  16777216u
#define W2HI_OFF  25165824u
#define W2LO_OFF  (25165824u + 200704u)
#define WS_NEEDED (25165824u + 2u * 200704u)

__device__ __forceinline__ unsigned short bf16_rne(float f) {
    uint32_t u = __float_as_uint(f);
    uint32_t r = u + 0x7FFFu + ((u >> 16) & 1u);
    return (unsigned short)(r >> 16);
}

// LIF membrane update with XLA-matching rounding: sub, mul(exact /2), add each
// rounded separately. contract(off) prevents hipcc's default fma fusion, which
// would change rounding before the v>=0.5 threshold compares.
__device__ __forceinline__ float lif_update(float v, float inp) {
#pragma clang fp contract(off)
    float dv = (inp - v) * 0.5f;
    float vn = v + dv;
    return vn;
}

// ---------------- K0: split dec_w2 into hi/lo bf16 ----------------
__global__ __launch_bounds__(256) void splitW(const float* __restrict__ w,
                                              unsigned short* __restrict__ hi,
                                              unsigned short* __restrict__ lo, int n) {
    int i = blockIdx.x * 256 + threadIdx.x;
    if (i < n) {
        float v = w[i];
        unsigned short h = bf16_rne(v);
        float hf = __uint_as_float(((uint32_t)h) << 16);
        hi[i] = h;
        lo[i] = bf16_rne(v - hf);   // v-hf exact (Sterbenz), residual rounds to bf16
    }
}

// ---------------- K1: x_in = x @ enc_w1^T + b1 (fp32 exact) ----------------
// tile M=64 (rows of x), N=128 (all H), BK=32. 256 thr, each 4m x 8n.
__global__ __launch_bounds__(256) void phaseA(const float* __restrict__ x,
                                              const float* __restrict__ w1,
                                              const float* __restrict__ b1,
                                              float* __restrict__ xin) {
    __shared__ float xs[64 * 36];    // stride 36 floats: 16B-aligned rows, bank-spread
    __shared__ float wsm[128 * 36];
    const int tid = threadIdx.x;
    const int bm = blockIdx.x * 64;
    const int tm = tid >> 4;   // 0..15
    const int tn = tid & 15;   // 0..15
    float acc[4][8];
#pragma unroll
    for (int m = 0; m < 4; m++)
#pragma unroll
        for (int n = 0; n < 8; n++) acc[m][n] = 0.f;

    for (int k0 = 0; k0 < 784; k0 += 32) {
#pragma unroll
        for (int i = 0; i < 2; i++) {           // x tile: 64x32 = 512 float4
            int idx = tid + 256 * i;
            int r = idx >> 3, kq = idx & 7;
            float4 v = make_float4(0.f, 0.f, 0.f, 0.f);
            int k = k0 + kq * 4;
            if (k < 784) v = *reinterpret_cast<const float4*>(&x[(size_t)(bm + r) * 784 + k]);
            *reinterpret_cast<float4*>(&xs[r * 36 + kq * 4]) = v;
        }
#pragma unroll
        for (int i = 0; i < 4; i++) {           // w tile: 128x32 = 1024 float4
            int idx = tid + 256 * i;
            int r = idx >> 3, kq = idx & 7;
            float4 v = make_float4(0.f, 0.f, 0.f, 0.f);
            int k = k0 + kq * 4;
            if (k < 784) v = *reinterpret_cast<const float4*>(&w1[(size_t)r * 784 + k]);
            *reinterpret_cast<float4*>(&wsm[r * 36 + kq * 4]) = v;
        }
        __syncthreads();
#pragma unroll
        for (int kk = 0; kk < 8; kk++) {
            float4 a4[4], b4[8];
#pragma unroll
            for (int m = 0; m < 4; m++)
                a4[m] = *reinterpret_cast<const float4*>(&xs[(tm * 4 + m) * 36 + kk * 4]);
#pragma unroll
            for (int n = 0; n < 8; n++)
                b4[n] = *reinterpret_cast<const float4*>(&wsm[(tn + 16 * n) * 36 + kk * 4]);
#pragma unroll
            for (int m = 0; m < 4; m++)
#pragma unroll
                for (int n = 0; n < 8; n++)
                    acc[m][n] += a4[m].x * b4[n].x + a4[m].y * b4[n].y +
                                 a4[m].z * b4[n].z + a4[m].w * b4[n].w;
        }
        __syncthreads();
    }
#pragma unroll
    for (int n = 0; n < 8; n++) {
        float bias = b1[tn + 16 * n];
#pragma unroll
        for (int m = 0; m < 4; m++)
            xin[(size_t)(bm + tm * 4 + m) * 128 + tn + 16 * n] = acc[m][n] + bias;
    }
}

// ---------------- K2: LIF recurrence, one wave per sample ----------------
// lane L holds neurons {L, L+64} of v1/v3; v2[L&31] duplicated across halves.
// Masked column sums over ballot masks are wave-uniform -> scalar bit loops,
// ascending k order == sequential dense dot (adding exact 0 terms is a no-op),
// bias added last to match reference's (sum)+bias grouping.
__global__ __launch_bounds__(256) void phaseB(const float* __restrict__ xin,
                                              const float* __restrict__ w2,   // enc_w2 [32][128]
                                              const float* __restrict__ b2,   // enc_b2 [32]
                                              const float* __restrict__ dw1,  // dec_w1 [128][32]
                                              const float* __restrict__ db1,  // dec_b1 [128]
                                              ulonglong2* __restrict__ masks) {
    __shared__ float w2t[128 * 32];   // [k][l] = enc_w2[l][k]
    __shared__ float dw1t[32 * 128];  // [l][k] = dec_w1[k][l]
    const int tid = threadIdx.x;
    for (int i = tid; i < 4096; i += 256) {
        { int l = i >> 7, k = i & 127; w2t[k * 32 + l] = w2[i]; }     // w2[i]=w2[l][k], coalesced read
        { int k = i >> 5, l = i & 31; dw1t[l * 128 + k] = dw1[i]; }   // dw1[i]=dw1[k][l], coalesced read
    }
    __syncthreads();
    const int L = tid & 63;
    const int s = blockIdx.x * 4 + (tid >> 6);
    const int l5 = L & 31;
    float xa = xin[(size_t)s * 128 + L];
    float xb = xin[(size_t)s * 128 + 64 + L];
    float b2v = b2[l5];
    float db1a = db1[L], db1b = db1[L + 64];
    float v1a = 0.f, v1b = 0.f, v2 = 0.f, v3a = 0.f, v3b = 0.f;

    for (int t = 0; t < 16; t++) {
        v1a = lif_update(v1a, xa);
        v1b = lif_update(v1b, xb);
        bool sa = v1a >= 0.5f, sb = v1b >= 0.5f;
        v1a = sa ? 0.f : v1a;
        v1b = sb ? 0.f : v1b;
        unsigned long long m0 = __ballot(sa), m1 = __ballot(sb);
        float zp = 0.f;
        unsigned long long mm = m0;
        while (mm) { int k = __builtin_ctzll(mm); mm &= mm - 1; zp += w2t[k * 32 + l5]; }
        mm = m1;
        while (mm) { int k = __builtin_ctzll(mm); mm &= mm - 1; zp += w2t[(k + 64) * 32 + l5]; }
        v2 = lif_update(v2, zp + b2v);
        bool sz = v2 >= 0.5f;
        v2 = sz ? 0.f : v2;
        uint32_t zm = (uint32_t)__ballot(sz);   // lanes 32..63 mirror 0..31; low 32 bits valid
        float dpa = 0.f, dpb = 0.f;
        uint32_t m = zm;
        while (m) {
            int l = __builtin_ctz(m); m &= m - 1;
            dpa += dw1t[l * 128 + L];
            dpb += dw1t[l * 128 + 64 + L];
        }
        v3a = lif_update(v3a, dpa + db1a);
        v3b = lif_update(v3b, dpb + db1b);
        bool da = v3a >= 0.5f, db_ = v3b >= 0.5f;
        v3a = da ? 0.f : v3a;
        v3b = db_ ? 0.f : v3b;
        unsigned long long d0 = __ballot(da), d1 = __ballot(db_);
        if (L == 0) {
            ulonglong2 v; v.x = d0; v.y = d1;
            masks[(size_t)s * 16 + t] = v;
        }
    }
}

// ---------------- K3: decoder recon via bf16 MFMA ----------------
// block: 8 samples -> M=128 rows (sample*16 + t). Spikes unpacked to swizzled
// LDS bf16 once, A-frags hoisted to regs (8 m-subtiles x 4 k-steps).
// Each wave owns N-tiles jt = wave, wave+4, ... (49 tiles of 16 cols).
// Epilogue fuses +dec_b2, sigmoid, reduce over t (rows), /16, single write.
__global__ __launch_bounds__(256, 2) void phaseC(const ulonglong2* __restrict__ masks,
                                                 const unsigned short* __restrict__ w2hi,
                                                 const unsigned short* __restrict__ w2lo,
                                                 const float* __restrict__ b2,  // dec_b2 [784]
                                                 float* __restrict__ out) {
    __shared__ unsigned short As[128 * 128];   // 32 KB, rows XOR-swizzled
    const int tid = threadIdx.x;
    const int s0 = blockIdx.x * 8;
    {
        int r = tid >> 1;            // row 0..127  (sample = r>>4, t = r&15)
        int h = tid & 1;             // which u64 half (k 0..63 / 64..127)
        const unsigned long long* mp = reinterpret_cast<const unsigned long long*>(masks);
        unsigned long long m = mp[((size_t)s0 * 16 + r) * 2 + h];
#pragma unroll
        for (int i = 0; i < 8; i++) {
            uint32_t b = (uint32_t)(m >> (i * 8)) & 0xFFu;
            uint4 val;
            val.x = ((b & 1u)  ? 0x3F80u : 0u) | ((b & 2u)   ? 0x3F800000u : 0u);
            val.y = ((b & 4u)  ? 0x3F80u : 0u) | ((b & 8u)   ? 0x3F800000u : 0u);
            val.z = ((b & 16u) ? 0x3F80u : 0u) | ((b & 32u)  ? 0x3F800000u : 0u);
            val.w = ((b & 64u) ? 0x3F80u : 0u) | ((b & 128u) ? 0x3F800000u : 0u);
            int byte = r * 256 + h * 128 + i * 16;
            byte ^= (r & 7) << 4;
            *reinterpret_cast<uint4*>(reinterpret_cast<char*>(As) + byte) = val;
        }
    }
    __syncthreads();
    const int wv = tid >> 6;
    const int L = tid & 63;
    const int col = L & 15;
    const int g = L >> 4;            // k-group 0..3
    // hoist all A fragments: lane holds A[row=mi*16+col][k = kk*32 + g*8 + 0..7]
    short8 af[8][4];
#pragma unroll
    for (int mi = 0; mi < 8; mi++) {
        int r = mi * 16 + col;
#pragma unroll
        for (int kk = 0; kk < 4; kk++) {
            int byte = r * 256 + kk * 64 + g * 16;
            byte ^= (r & 7) << 4;
            af[mi][kk] = *reinterpret_cast<const short8*>(reinterpret_cast<const char*>(As) + byte);
        }
    }
    for (int jt = wv; jt < 49; jt += 4) {
        const int j0 = jt * 16;
        const int j = j0 + col;
        short8 bh[4], bl[4];
#pragma unroll
        for (int kk = 0; kk < 4; kk++) {
            int off = j * 128 + kk * 32 + g * 8;
            bh[kk] = *reinterpret_cast<const short8*>(&w2hi[off]);
            bl[kk] = *reinterpret_cast<const short8*>(&w2lo[off]);
        }
        const float bias = b2[j];
#pragma unroll
        for (int mi = 0; mi < 8; mi++) {
            f32x4 acc = {0.f, 0.f, 0.f, 0.f};
#pragma unroll
            for (int kk = 0; kk < 4; kk++) {
                acc = __builtin_amdgcn_mfma_f32_16x16x32_bf16(af[mi][kk], bh[kk], acc, 0, 0, 0);
                acc = __builtin_amdgcn_mfma_f32_16x16x32_bf16(af[mi][kk], bl[kk], acc, 0, 0, 0);
            }
            // C layout: col = L&15, row(t) = g*4 + i. Sum sigmoid over t.
            float p = 0.f;
#pragma unroll
            for (int i = 0; i < 4; i++) {
                float val = acc[i] + bias;
                p += 1.0f / (1.0f + __expf(-val));
            }
            p += __shfl_xor(p, 16);
            p += __shfl_xor(p, 32);
            if (L < 16) out[(size_t)(s0 + mi) * 784 + j0 + col] = p * 0.0625f;
        }
    }
}

extern "C" void kernel_launch(void* const* d_in, const int* in_sizes, int n_in,
                              void* d_out, int out_size, void* d_ws, size_t ws_size,
                              hipStream_t stream) {
    // Diagnostic guard: if the harness workspace is smaller than our layout,
    // launching would write OOB and could kill the container. Launch nothing
    // instead -> harness reports a clean "incorrect" (out stays poisoned),
    // which tells us ws_size was the problem.
    if (ws_size < (size_t)WS_NEEDED) return;

    const float* x   = (const float*)d_in[0];
    const float* ew1 = (const float*)d_in[1];
    const float* eb1 = (const float*)d_in[2];
    const float* ew2 = (const float*)d_in[3];
    const float* eb2 = (const float*)d_in[4];
    const float* dw1 = (const float*)d_in[5];
    const float* db1 = (const float*)d_in[6];
    const float* dw2 = (const float*)d_in[7];
    const float* db2 = (const float*)d_in[8];
    float* out = (float*)d_out;
    char* ws = (char*)d_ws;

    float* xin            = (float*)(ws + XIN_OFF);
    ulonglong2* masks     = (ulonglong2*)(ws + MASK_OFF);
    unsigned short* w2hi  = (unsigned short*)(ws + W2HI_OFF);
    unsigned short* w2lo  = (unsigned short*)(ws + W2LO_OFF);

    splitW<<<dim3(392), dim3(256), 0, stream>>>(dw2, w2hi, w2lo, 784 * 128);
    phaseA<<<dim3(512), dim3(256), 0, stream>>>(x, ew1, eb1, xin);
    phaseB<<<dim3(8192), dim3(256), 0, stream>>>(xin, ew2, eb2, dw1, db1, masks);
    phaseC<<<dim3(4096), dim3(256), 0, stream>>>(masks, w2hi, w2lo, db2, out);
}

// Round 6
// 870.795 us; speedup vs baseline: 1.0207x; 1.0207x over previous
//
#include <hip/hip_runtime.h>
#include <cstdint>

// SNN autoencoder, MI355X. 4 kernels:
//  K0 splitW : dec_w2 (fp32) -> hi/lo bf16 pair of (-log2e * w)  [2^-18 rel]
//  K1 phaseA : x_in = x @ enc_w1^T + enc_b1, exact fp32 tiled GEMM
//  K2 phaseB : per-sample LIF recurrence (wave/sample, state in regs),
//              emits d1 spike masks. Bit-order kept EXACT (absmax was 0.0).
//  K3 phaseC : out = mean_t sigmoid(spikes_t @ dec_w2^T + dec_b2) via bf16 MFMA
//              acc = -log2e*(S.W+b) -> sigma = rcp(1 + exp2(acc)); bias in acc-init.
// R5 counters: phaseC 417us, VALUBusy 58% vs MfmaUtil 21%, Occupancy 21%.
//   -> IEEE fdiv sequence + broken af hoist + launch_bounds(256,2) occupancy.
//   Fix: exp2/rcp epilogue, half-pass mi split (af=64 VGPR), bounds(256,4).
// ws layout (25,567,232 bytes; guarded):
//  [0, 16MB) x_in fp32 [32768][128] | [16MB,24MB) masks ull2 [32768][16]
//  [24MB..]  w2hi, w2lo ushort [784][128] each (scaled by -log2e)

using short8 = __attribute__((ext_vector_type(8))) short;
using f32x4  = __attribute__((ext_vector_type(4))) float;

#define XIN_OFF   0u
#define MASK_OFF  16777216u
#define W2HI_OFF  25165824u
#define W2LO_OFF  (25165824u + 200704u)
#define WS_NEEDED (25165824u + 2u * 200704u)

#define NLOG2E (-1.4426950408889634f)

__device__ __forceinline__ unsigned short bf16_rne(float f) {
    uint32_t u = __float_as_uint(f);
    uint32_t r = u + 0x7FFFu + ((u >> 16) & 1u);
    return (unsigned short)(r >> 16);
}

__device__ __forceinline__ float fast_exp2(float x) {
#if __has_builtin(__builtin_amdgcn_exp2f)
    return __builtin_amdgcn_exp2f(x);
#else
    return exp2f(x);
#endif
}
__device__ __forceinline__ float fast_rcp(float x) {
#if __has_builtin(__builtin_amdgcn_rcpf)
    return __builtin_amdgcn_rcpf(x);
#else
    return 1.0f / x;
#endif
}

// LIF membrane update with XLA-matching rounding (no fma contraction).
__device__ __forceinline__ float lif_update(float v, float inp) {
#pragma clang fp contract(off)
    float dv = (inp - v) * 0.5f;
    float vn = v + dv;
    return vn;
}

// ---------------- K0: split -log2e*dec_w2 into hi/lo bf16 ----------------
__global__ __launch_bounds__(256) void splitW(const float* __restrict__ w,
                                              unsigned short* __restrict__ hi,
                                              unsigned short* __restrict__ lo, int n) {
    int i = blockIdx.x * 256 + threadIdx.x;
    if (i < n) {
        float v = w[i] * NLOG2E;
        unsigned short h = bf16_rne(v);
        float hf = __uint_as_float(((uint32_t)h) << 16);
        hi[i] = h;
        lo[i] = bf16_rne(v - hf);   // v-hf exact (Sterbenz), residual rounds to bf16
    }
}

// ---------------- K1: x_in = x @ enc_w1^T + b1 (fp32 exact) ----------------
__global__ __launch_bounds__(256) void phaseA(const float* __restrict__ x,
                                              const float* __restrict__ w1,
                                              const float* __restrict__ b1,
                                              float* __restrict__ xin) {
    __shared__ float xs[64 * 36];
    __shared__ float wsm[128 * 36];
    const int tid = threadIdx.x;
    const int bm = blockIdx.x * 64;
    const int tm = tid >> 4;
    const int tn = tid & 15;
    float acc[4][8];
#pragma unroll
    for (int m = 0; m < 4; m++)
#pragma unroll
        for (int n = 0; n < 8; n++) acc[m][n] = 0.f;

    for (int k0 = 0; k0 < 784; k0 += 32) {
#pragma unroll
        for (int i = 0; i < 2; i++) {
            int idx = tid + 256 * i;
            int r = idx >> 3, kq = idx & 7;
            float4 v = make_float4(0.f, 0.f, 0.f, 0.f);
            int k = k0 + kq * 4;
            if (k < 784) v = *reinterpret_cast<const float4*>(&x[(size_t)(bm + r) * 784 + k]);
            *reinterpret_cast<float4*>(&xs[r * 36 + kq * 4]) = v;
        }
#pragma unroll
        for (int i = 0; i < 4; i++) {
            int idx = tid + 256 * i;
            int r = idx >> 3, kq = idx & 7;
            float4 v = make_float4(0.f, 0.f, 0.f, 0.f);
            int k = k0 + kq * 4;
            if (k < 784) v = *reinterpret_cast<const float4*>(&w1[(size_t)r * 784 + k]);
            *reinterpret_cast<float4*>(&wsm[r * 36 + kq * 4]) = v;
        }
        __syncthreads();
#pragma unroll
        for (int kk = 0; kk < 8; kk++) {
            float4 a4[4], b4[8];
#pragma unroll
            for (int m = 0; m < 4; m++)
                a4[m] = *reinterpret_cast<const float4*>(&xs[(tm * 4 + m) * 36 + kk * 4]);
#pragma unroll
            for (int n = 0; n < 8; n++)
                b4[n] = *reinterpret_cast<const float4*>(&wsm[(tn + 16 * n) * 36 + kk * 4]);
#pragma unroll
            for (int m = 0; m < 4; m++)
#pragma unroll
                for (int n = 0; n < 8; n++)
                    acc[m][n] += a4[m].x * b4[n].x + a4[m].y * b4[n].y +
                                 a4[m].z * b4[n].z + a4[m].w * b4[n].w;
        }
        __syncthreads();
    }
#pragma unroll
    for (int n = 0; n < 8; n++) {
        float bias = b1[tn + 16 * n];
#pragma unroll
        for (int m = 0; m < 4; m++)
            xin[(size_t)(bm + tm * 4 + m) * 128 + tn + 16 * n] = acc[m][n] + bias;
    }
}

// ---------------- K2: LIF recurrence (UNCHANGED — absmax 0.0 exact) ----------------
__global__ __launch_bounds__(256) void phaseB(const float* __restrict__ xin,
                                              const float* __restrict__ w2,
                                              const float* __restrict__ b2,
                                              const float* __restrict__ dw1,
                                              const float* __restrict__ db1,
                                              ulonglong2* __restrict__ masks) {
    __shared__ float w2t[128 * 32];
    __shared__ float dw1t[32 * 128];
    const int tid = threadIdx.x;
    for (int i = tid; i < 4096; i += 256) {
        { int l = i >> 7, k = i & 127; w2t[k * 32 + l] = w2[i]; }
        { int k = i >> 5, l = i & 31; dw1t[l * 128 + k] = dw1[i]; }
    }
    __syncthreads();
    const int L = tid & 63;
    const int s = blockIdx.x * 4 + (tid >> 6);
    const int l5 = L & 31;
    float xa = xin[(size_t)s * 128 + L];
    float xb = xin[(size_t)s * 128 + 64 + L];
    float b2v = b2[l5];
    float db1a = db1[L], db1b = db1[L + 64];
    float v1a = 0.f, v1b = 0.f, v2 = 0.f, v3a = 0.f, v3b = 0.f;

    for (int t = 0; t < 16; t++) {
        v1a = lif_update(v1a, xa);
        v1b = lif_update(v1b, xb);
        bool sa = v1a >= 0.5f, sb = v1b >= 0.5f;
        v1a = sa ? 0.f : v1a;
        v1b = sb ? 0.f : v1b;
        unsigned long long m0 = __ballot(sa), m1 = __ballot(sb);
        float zp = 0.f;
        unsigned long long mm = m0;
        while (mm) { int k = __builtin_ctzll(mm); mm &= mm - 1; zp += w2t[k * 32 + l5]; }
        mm = m1;
        while (mm) { int k = __builtin_ctzll(mm); mm &= mm - 1; zp += w2t[(k + 64) * 32 + l5]; }
        v2 = lif_update(v2, zp + b2v);
        bool sz = v2 >= 0.5f;
        v2 = sz ? 0.f : v2;
        uint32_t zm = (uint32_t)__ballot(sz);
        float dpa = 0.f, dpb = 0.f;
        uint32_t m = zm;
        while (m) {
            int l = __builtin_ctz(m); m &= m - 1;
            dpa += dw1t[l * 128 + L];
            dpb += dw1t[l * 128 + 64 + L];
        }
        v3a = lif_update(v3a, dpa + db1a);
        v3b = lif_update(v3b, dpb + db1b);
        bool da = v3a >= 0.5f, db_ = v3b >= 0.5f;
        v3a = da ? 0.f : v3a;
        v3b = db_ ? 0.f : v3b;
        unsigned long long d0 = __ballot(da), d1 = __ballot(db_);
        if (L == 0) {
            ulonglong2 v; v.x = d0; v.y = d1;
            masks[(size_t)s * 16 + t] = v;
        }
    }
}

// ---------------- K3: decoder recon via bf16 MFMA ----------------
// Two half-passes of 4 m-subtiles: af[4][4] = 64 VGPR genuinely hoisted.
// acc init = bias*(-log2e); sigma = rcp(1+exp2(acc)) — no IEEE div, no mul.
__global__ __launch_bounds__(256, 4) void phaseC(const ulonglong2* __restrict__ masks,
                                                 const unsigned short* __restrict__ w2hi,
                                                 const unsigned short* __restrict__ w2lo,
                                                 const float* __restrict__ b2,
                                                 float* __restrict__ out) {
    __shared__ unsigned short As[128 * 128];   // 32 KB, rows XOR-swizzled
    const int tid = threadIdx.x;
    const int s0 = blockIdx.x * 8;
    {
        int r = tid >> 1;            // row 0..127  (sample = r>>4, t = r&15)
        int h = tid & 1;
        const unsigned long long* mp = reinterpret_cast<const unsigned long long*>(masks);
        unsigned long long m = mp[((size_t)s0 * 16 + r) * 2 + h];
#pragma unroll
        for (int i = 0; i < 8; i++) {
            uint32_t b = (uint32_t)(m >> (i * 8)) & 0xFFu;
            uint4 val;
            val.x = ((b & 1u)  ? 0x3F80u : 0u) | ((b & 2u)   ? 0x3F800000u : 0u);
            val.y = ((b & 4u)  ? 0x3F80u : 0u) | ((b & 8u)   ? 0x3F800000u : 0u);
            val.z = ((b & 16u) ? 0x3F80u : 0u) | ((b & 32u)  ? 0x3F800000u : 0u);
            val.w = ((b & 64u) ? 0x3F80u : 0u) | ((b & 128u) ? 0x3F800000u : 0u);
            int byte = r * 256 + h * 128 + i * 16;
            byte ^= (r & 7) << 4;
            *reinterpret_cast<uint4*>(reinterpret_cast<char*>(As) + byte) = val;
        }
    }
    __syncthreads();
    const int wv = tid >> 6;
    const int L = tid & 63;
    const int col = L & 15;
    const int g = L >> 4;            // k-group 0..3

#pragma unroll 1
    for (int hf = 0; hf < 2; hf++) {           // half-pass: samples s0+4hf .. +3
        short8 af[4][4];                        // 64 VGPR, truly hoisted
#pragma unroll
        for (int mi = 0; mi < 4; mi++) {
            int r = (hf * 4 + mi) * 16 + col;
#pragma unroll
            for (int kk = 0; kk < 4; kk++) {
                int byte = r * 256 + kk * 64 + g * 16;
                byte ^= (r & 7) << 4;
                af[mi][kk] = *reinterpret_cast<const short8*>(reinterpret_cast<const char*>(As) + byte);
            }
        }
        for (int jt = wv; jt < 49; jt += 4) {
            const int j0 = jt * 16;
            const int j = j0 + col;
            short8 bh[4], bl[4];
#pragma unroll
            for (int kk = 0; kk < 4; kk++) {
                int off = j * 128 + kk * 32 + g * 8;
                bh[kk] = *reinterpret_cast<const short8*>(&w2hi[off]);
                bl[kk] = *reinterpret_cast<const short8*>(&w2lo[off]);
            }
            const float bias2 = b2[j] * NLOG2E;
#pragma unroll
            for (int mi = 0; mi < 4; mi++) {
                f32x4 acc = {bias2, bias2, bias2, bias2};
#pragma unroll
                for (int kk = 0; kk < 4; kk++) {
                    acc = __builtin_amdgcn_mfma_f32_16x16x32_bf16(af[mi][kk], bh[kk], acc, 0, 0, 0);
                    acc = __builtin_amdgcn_mfma_f32_16x16x32_bf16(af[mi][kk], bl[kk], acc, 0, 0, 0);
                }
                // acc[i] = -log2e*(S.W + b) at (row t=g*4+i, col j). sigma=rcp(1+2^acc).
                float p = 0.f;
#pragma unroll
                for (int i = 0; i < 4; i++) {
                    float e = fast_exp2(acc[i]);
                    p += fast_rcp(1.0f + e);
                }
                p += __shfl_xor(p, 16);
                p += __shfl_xor(p, 32);
                if (L < 16) out[(size_t)(s0 + hf * 4 + mi) * 784 + j0 + col] = p * 0.0625f;
            }
        }
    }
}

extern "C" void kernel_launch(void* const* d_in, const int* in_sizes, int n_in,
                              void* d_out, int out_size, void* d_ws, size_t ws_size,
                              hipStream_t stream) {
    if (ws_size < (size_t)WS_NEEDED) return;   // OOB guard (keeps container alive)

    const float* x   = (const float*)d_in[0];
    const float* ew1 = (const float*)d_in[1];
    const float* eb1 = (const float*)d_in[2];
    const float* ew2 = (const float*)d_in[3];
    const float* eb2 = (const float*)d_in[4];
    const float* dw1 = (const float*)d_in[5];
    const float* db1 = (const float*)d_in[6];
    const float* dw2 = (const float*)d_in[7];
    const float* db2 = (const float*)d_in[8];
    float* out = (float*)d_out;
    char* ws = (char*)d_ws;

    float* xin            = (float*)(ws + XIN_OFF);
    ulonglong2* masks     = (ulonglong2*)(ws + MASK_OFF);
    unsigned short* w2hi  = (unsigned short*)(ws + W2HI_OFF);
    unsigned short* w2lo  = (unsigned short*)(ws + W2LO_OFF);

    splitW<<<dim3(392), dim3(256), 0, stream>>>(dw2, w2hi, w2lo, 784 * 128);
    phaseA<<<dim3(512), dim3(256), 0, stream>>>(x, ew1, eb1, xin);
    phaseB<<<dim3(8192), dim3(256), 0, stream>>>(xin, ew2, eb2, dw1, db1, masks);
    phaseC<<<dim3(4096), dim3(256), 0, stream>>>(masks, w2hi, w2lo, db2, out);
}

// Round 12
// 608.723 us; speedup vs baseline: 1.4602x; 1.4305x over previous
//
#include <hip/hip_runtime.h>
#include <cstdint>

// SNN autoencoder, MI355X. 4 kernels:
//  K0 convW  : dec_w2 (fp32) -> fp16 of (-log2e * w)   [delta <= 2^-11 rel]
//  K1 phaseA : x_in = x @ enc_w1^T + enc_b1, fp32 128x128 tile, 8x8/thread,
//              k-major LDS, reg-staged double buffer (VALU-bound, not LDS-bound)
//  K2 phaseB : per-sample LIF recurrence (UNCHANGED, bit-exact anchor)
//  K3 phaseC : out = mean_t sigmoid(spikes_t @ dec_w2^T + dec_b2) via fp16 MFMA.
//              NO LDS: A expanded from masks in registers; B register-prefetched.
//              Epilogue bit-identical to R6 (absmax 0.0): rcp(1+exp2(-log2e*z)).
// R6 counters: phaseC 385us, MfmaUtil 22%, VALU 29%, VGPR=64 -> af hoist failed,
//   LDS re-read per jt + unpipelined B loads = latency-bound. This round removes
//   the LDS path entirely and pipelines B.
// R8: fixed compile error (__half w/o hip_fp16.h) -> native _Float16 cast.
// R11 note: R6 accounting leaves ~400us unattributed (phaseB?) — awaiting its
//   counters before touching it (candidates: readfirstlane SGPR bit-loops).
// ws layout (guard 25.6MB; actually used 24.2MB):
//  [0,16MB) x_in fp32 [32768][128] | [16MB,24MB) masks ull2 [32768][16]
//  [24MB..] w2h ushort(fp16) [784][128]

using short8 = __attribute__((ext_vector_type(8))) short;
using half8  = __attribute__((ext_vector_type(8))) _Float16;
using f32x4  = __attribute__((ext_vector_type(4))) float;

#define XIN_OFF   0u
#define MASK_OFF  16777216u
#define W2H_OFF   25165824u
#define WS_NEEDED (25165824u + 2u * 200704u)

#define NLOG2E (-1.4426950408889634f)

__device__ __forceinline__ float fast_exp2(float x) {
#if __has_builtin(__builtin_amdgcn_exp2f)
    return __builtin_amdgcn_exp2f(x);
#else
    return exp2f(x);
#endif
}
__device__ __forceinline__ float fast_rcp(float x) {
#if __has_builtin(__builtin_amdgcn_rcpf)
    return __builtin_amdgcn_rcpf(x);
#else
    return 1.0f / x;
#endif
}

// LIF membrane update with XLA-matching rounding (no fma contraction).
__device__ __forceinline__ float lif_update(float v, float inp) {
#pragma clang fp contract(off)
    float dv = (inp - v) * 0.5f;
    float vn = v + dv;
    return vn;
}

// ---------------- K0: convert -log2e*dec_w2 to fp16 ----------------
__global__ __launch_bounds__(256) void convW(const float* __restrict__ w,
                                             unsigned short* __restrict__ wh, int n) {
    int i = blockIdx.x * 256 + threadIdx.x;
    if (i < n) {
        _Float16 h = (_Float16)(w[i] * NLOG2E);   // v_cvt_f16_f32, RNE
        wh[i] = __builtin_bit_cast(unsigned short, h);
    }
}

// ---------------- K1: x_in = x @ enc_w1^T + b1 (fp32) ----------------
// 256 blocks, tile M=128 x N=128(all H), BK=16 (784 = 49*16 exact).
// k-major LDS [16][132]; per thread 8x8; reg-staged double buffer.
__global__ __launch_bounds__(256) void phaseA(const float* __restrict__ x,
                                              const float* __restrict__ w1,
                                              const float* __restrict__ b1,
                                              float* __restrict__ xin) {
    __shared__ float xs[2][16 * 132];
    __shared__ float wsm[2][16 * 132];
    const int tid = threadIdx.x;
    const int bm = blockIdx.x * 128;
    const int tm = tid >> 4;   // 0..15
    const int tn = tid & 15;   // 0..15

    float acc[8][8];
#pragma unroll
    for (int m = 0; m < 8; m++)
#pragma unroll
        for (int n = 0; n < 8; n++) acc[m][n] = 0.f;

    float4 rx[2], rw[2];
    // stage s -> regs
#define LOADG(s)                                                                  \
    {                                                                             \
        _Pragma("unroll") for (int i = 0; i < 2; i++) {                           \
            int idx = tid + 256 * i;                                              \
            int r = idx >> 2, kq = idx & 3;                                       \
            rx[i] = *reinterpret_cast<const float4*>(&x[(size_t)(bm + r) * 784 + (s)*16 + kq * 4]);  \
            rw[i] = *reinterpret_cast<const float4*>(&w1[(size_t)r * 784 + (s)*16 + kq * 4]);        \
        }                                                                         \
    }
    // regs -> LDS buf (k-major, transpose)
#define STOREL(buf)                                                               \
    {                                                                             \
        _Pragma("unroll") for (int i = 0; i < 2; i++) {                           \
            int idx = tid + 256 * i;                                              \
            int r = idx >> 2, kq = idx & 3;                                       \
            float* xp = &xs[buf][0];                                              \
            float* wp = &wsm[buf][0];                                             \
            xp[(kq * 4 + 0) * 132 + r] = rx[i].x;                                 \
            xp[(kq * 4 + 1) * 132 + r] = rx[i].y;                                 \
            xp[(kq * 4 + 2) * 132 + r] = rx[i].z;                                 \
            xp[(kq * 4 + 3) * 132 + r] = rx[i].w;                                 \
            wp[(kq * 4 + 0) * 132 + r] = rw[i].x;                                 \
            wp[(kq * 4 + 1) * 132 + r] = rw[i].y;                                 \
            wp[(kq * 4 + 2) * 132 + r] = rw[i].z;                                 \
            wp[(kq * 4 + 3) * 132 + r] = rw[i].w;                                 \
        }                                                                         \
    }

    LOADG(0);
    STOREL(0);
    __syncthreads();

    for (int s = 0; s < 49; s++) {
        const int buf = s & 1;
        if (s + 1 < 49) LOADG(s + 1);   // prefetch overlaps compute
#pragma unroll
        for (int kk = 0; kk < 16; kk++) {
            float4 a0 = *reinterpret_cast<const float4*>(&xs[buf][kk * 132 + tm * 8]);
            float4 a1 = *reinterpret_cast<const float4*>(&xs[buf][kk * 132 + tm * 8 + 4]);
            float4 b0 = *reinterpret_cast<const float4*>(&wsm[buf][kk * 132 + tn * 8]);
            float4 b1v = *reinterpret_cast<const float4*>(&wsm[buf][kk * 132 + tn * 8 + 4]);
            float a[8] = {a0.x, a0.y, a0.z, a0.w, a1.x, a1.y, a1.z, a1.w};
            float b[8] = {b0.x, b0.y, b0.z, b0.w, b1v.x, b1v.y, b1v.z, b1v.w};
#pragma unroll
            for (int m = 0; m < 8; m++)
#pragma unroll
                for (int n = 0; n < 8; n++) acc[m][n] = fmaf(a[m], b[n], acc[m][n]);
        }
        if (s + 1 < 49) {
            __syncthreads();            // all waves done reading buf^1 (from s-1)
            STOREL((s + 1) & 1);
            __syncthreads();            // next tile visible
        }
    }

    float bv[8];
#pragma unroll
    for (int n = 0; n < 8; n++) bv[n] = b1[tn * 8 + n];
#pragma unroll
    for (int m = 0; m < 8; m++) {
        size_t row = (size_t)(bm + tm * 8 + m);
        float4 o0, o1;
        o0.x = acc[m][0] + bv[0]; o0.y = acc[m][1] + bv[1];
        o0.z = acc[m][2] + bv[2]; o0.w = acc[m][3] + bv[3];
        o1.x = acc[m][4] + bv[4]; o1.y = acc[m][5] + bv[5];
        o1.z = acc[m][6] + bv[6]; o1.w = acc[m][7] + bv[7];
        *reinterpret_cast<float4*>(&xin[row * 128 + tn * 8]) = o0;
        *reinterpret_cast<float4*>(&xin[row * 128 + tn * 8 + 4]) = o1;
    }
#undef LOADG
#undef STOREL
}

// ---------------- K2: LIF recurrence (UNCHANGED — bit-exact anchor) ----------------
__global__ __launch_bounds__(256) void phaseB(const float* __restrict__ xin,
                                              const float* __restrict__ w2,
                                              const float* __restrict__ b2,
                                              const float* __restrict__ dw1,
                                              const float* __restrict__ db1,
                                              ulonglong2* __restrict__ masks) {
    __shared__ float w2t[128 * 32];
    __shared__ float dw1t[32 * 128];
    const int tid = threadIdx.x;
    for (int i = tid; i < 4096; i += 256) {
        { int l = i >> 7, k = i & 127; w2t[k * 32 + l] = w2[i]; }
        { int k = i >> 5, l = i & 31; dw1t[l * 128 + k] = dw1[i]; }
    }
    __syncthreads();
    const int L = tid & 63;
    const int s = blockIdx.x * 4 + (tid >> 6);
    const int l5 = L & 31;
    float xa = xin[(size_t)s * 128 + L];
    float xb = xin[(size_t)s * 128 + 64 + L];
    float b2v = b2[l5];
    float db1a = db1[L], db1b = db1[L + 64];
    float v1a = 0.f, v1b = 0.f, v2 = 0.f, v3a = 0.f, v3b = 0.f;

    for (int t = 0; t < 16; t++) {
        v1a = lif_update(v1a, xa);
        v1b = lif_update(v1b, xb);
        bool sa = v1a >= 0.5f, sb = v1b >= 0.5f;
        v1a = sa ? 0.f : v1a;
        v1b = sb ? 0.f : v1b;
        unsigned long long m0 = __ballot(sa), m1 = __ballot(sb);
        float zp = 0.f;
        unsigned long long mm = m0;
        while (mm) { int k = __builtin_ctzll(mm); mm &= mm - 1; zp += w2t[k * 32 + l5]; }
        mm = m1;
        while (mm) { int k = __builtin_ctzll(mm); mm &= mm - 1; zp += w2t[(k + 64) * 32 + l5]; }
        v2 = lif_update(v2, zp + b2v);
        bool sz = v2 >= 0.5f;
        v2 = sz ? 0.f : v2;
        uint32_t zm = (uint32_t)__ballot(sz);
        float dpa = 0.f, dpb = 0.f;
        uint32_t m = zm;
        while (m) {
            int l = __builtin_ctz(m); m &= m - 1;
            dpa += dw1t[l * 128 + L];
            dpb += dw1t[l * 128 + 64 + L];
        }
        v3a = lif_update(v3a, dpa + db1a);
        v3b = lif_update(v3b, dpb + db1b);
        bool da = v3a >= 0.5f, db_ = v3b >= 0.5f;
        v3a = da ? 0.f : v3a;
        v3b = db_ ? 0.f : v3b;
        unsigned long long d0 = __ballot(da), d1 = __ballot(db_);
        if (L == 0) {
            ulonglong2 v; v.x = d0; v.y = d1;
            masks[(size_t)s * 16 + t] = v;
        }
    }
}

// ---------------- K3: decoder recon via fp16 MFMA, LDS-free ----------------
// Block = 8 samples (128 rows). Lane expands its A rows straight from the
// 16B mask words into fp16 fragments (af[4][4], 64 VGPR, per half-pass).
// B (w2h) register-prefetched one jt-tile ahead. Epilogue == R6 bitwise.
__global__ __launch_bounds__(256, 3) void phaseC(const ulonglong2* __restrict__ masks,
                                                 const unsigned short* __restrict__ w2h,
                                                 const float* __restrict__ b2,
                                                 float* __restrict__ out) {
    const int tid = threadIdx.x;
    const int s0 = blockIdx.x * 8;
    const int wv = tid >> 6;
    const int L = tid & 63;
    const int col = L & 15;
    const int g = L >> 4;            // k-group 0..3

#pragma unroll 1
    for (int hf = 0; hf < 2; hf++) {
        // A fragments: row r = hf*64 + mi*16 + col, k = kk*32 + g*8 + j
        half8 af[4][4];
#pragma unroll
        for (int mi = 0; mi < 4; mi++) {
            int r = hf * 64 + mi * 16 + col;
            ulonglong2 mk = masks[(size_t)s0 * 16 + r];
#pragma unroll
            for (int kk = 0; kk < 4; kk++) {
                unsigned long long w = (kk < 2) ? mk.x : mk.y;
                uint32_t b = (uint32_t)(w >> ((kk & 1) * 32 + g * 8)) & 0xFFu;
                uint4 v;
                v.x = ((b & 1u)  ? 0x3C00u : 0u) | ((b & 2u)   ? 0x3C000000u : 0u);
                v.y = ((b & 4u)  ? 0x3C00u : 0u) | ((b & 8u)   ? 0x3C000000u : 0u);
                v.z = ((b & 16u) ? 0x3C00u : 0u) | ((b & 32u)  ? 0x3C000000u : 0u);
                v.w = ((b & 64u) ? 0x3C00u : 0u) | ((b & 128u) ? 0x3C000000u : 0u);
                af[mi][kk] = *reinterpret_cast<half8*>(&v);
            }
        }
        // B prefetch pipeline over N-tiles
        half8 bn[4];
        {
            int j = wv * 16 + col;
#pragma unroll
            for (int kk = 0; kk < 4; kk++)
                bn[kk] = *reinterpret_cast<const half8*>(&w2h[(size_t)j * 128 + kk * 32 + g * 8]);
        }
        for (int jt = wv; jt < 49; jt += 4) {
            half8 bf[4];
#pragma unroll
            for (int kk = 0; kk < 4; kk++) bf[kk] = bn[kk];
            const float bias2 = b2[jt * 16 + col] * NLOG2E;
            if (jt + 4 < 49) {
                int j = (jt + 4) * 16 + col;
#pragma unroll
                for (int kk = 0; kk < 4; kk++)
                    bn[kk] = *reinterpret_cast<const half8*>(&w2h[(size_t)j * 128 + kk * 32 + g * 8]);
            }
#pragma unroll
            for (int mi = 0; mi < 4; mi++) {
                f32x4 acc = {bias2, bias2, bias2, bias2};
#pragma unroll
                for (int kk = 0; kk < 4; kk++)
                    acc = __builtin_amdgcn_mfma_f32_16x16x32_f16(af[mi][kk], bf[kk], acc, 0, 0, 0);
                // C layout: col=L&15, row(t)=g*4+i. Epilogue bitwise == R6.
                float p = 0.f;
#pragma unroll
                for (int i = 0; i < 4; i++) {
                    float e = fast_exp2(acc[i]);
                    p += fast_rcp(1.0f + e);
                }
                p += __shfl_xor(p, 16);
                p += __shfl_xor(p, 32);
                if (L < 16) out[(size_t)(s0 + hf * 4 + mi) * 784 + jt * 16 + col] = p * 0.0625f;
            }
        }
    }
}

extern "C" void kernel_launch(void* const* d_in, const int* in_sizes, int n_in,
                              void* d_out, int out_size, void* d_ws, size_t ws_size,
                              hipStream_t stream) {
    if (ws_size < (size_t)WS_NEEDED) return;   // OOB guard (keeps container alive)

    const float* x   = (const float*)d_in[0];
    const float* ew1 = (const float*)d_in[1];
    const float* eb1 = (const float*)d_in[2];
    const float* ew2 = (const float*)d_in[3];
    const float* eb2 = (const float*)d_in[4];
    const float* dw1 = (const float*)d_in[5];
    const float* db1 = (const float*)d_in[6];
    const float* dw2 = (const float*)d_in[7];
    const float* db2 = (const float*)d_in[8];
    float* out = (float*)d_out;
    char* ws = (char*)d_ws;

    float* xin           = (float*)(ws + XIN_OFF);
    ulonglong2* masks    = (ulonglong2*)(ws + MASK_OFF);
    unsigned short* w2h  = (unsigned short*)(ws + W2H_OFF);

    convW<<<dim3(392), dim3(256), 0, stream>>>(dw2, w2h, 784 * 128);
    phaseA<<<dim3(256), dim3(256), 0, stream>>>(x, ew1, eb1, xin);
    phaseB<<<dim3(8192), dim3(256), 0, stream>>>(xin, ew2, eb2, dw1, db1, masks);
    phaseC<<<dim3(4096), dim3(256), 0, stream>>>(masks, w2h, db2, out);
}